// Round 1
// baseline (601.667 us; speedup 1.0000x reference)
//
#include <hip/hip_runtime.h>
#include <hip/hip_bf16.h>

// EarthAttention3D (Pangu): B_=30, nW=32, N=144, C=192, H=6, hd=32
#define DIM    192
#define HEADS  6
#define HD     32
#define NTOK   144                  // tokens per window
#define NWIN   960                  // 30 lon * 32 window-types
#define NBWH   (NWIN * HEADS)       // 5760
#define TOKENS (NWIN * NTOK)        // 138240
#define PPITCH 168                  // LDS row pitch in halves: 336B = 21*16B aligned, 84 dwords -> only 2-way bank alias (free)

typedef __attribute__((ext_vector_type(8))) short bf16x8;   // 8 bf16 in 4 VGPRs (MFMA A/B frag)
typedef __attribute__((ext_vector_type(4))) float f32x4;    // MFMA C/D frag
typedef __attribute__((ext_vector_type(4))) short short4v;

static __device__ __forceinline__ short f2bf(float f) {
  __hip_bfloat16 h = __float2bfloat16(f);      // RTN
  return __builtin_bit_cast(short, h);
}
static __device__ __forceinline__ float bf2f(short s) {
  unsigned u = ((unsigned)(unsigned short)s) << 16;
  return __builtin_bit_cast(float, u);
}

// ---------------------------------------------------------------------------
// prep: cast weights to bf16 + expand positional bias gather once.
// bias_exp[w][h][i][j] = bias_table[pos_index[i][j]][w][h]   (bf16)
// ---------------------------------------------------------------------------
#define NBIAS (32 * HEADS * NTOK * NTOK)   // 3,981,312
#define NWQ   (3 * DIM * DIM)              // 110,592
#define NWP   (DIM * DIM)                  // 36,864

__global__ __launch_bounds__(256) void prep_kernel(
    const float* __restrict__ qkv_w, const float* __restrict__ proj_w,
    const float* __restrict__ bias_table, const int* __restrict__ pos_index,
    short* __restrict__ wq_b, short* __restrict__ wp_b, short* __restrict__ bias_exp)
{
  int i = blockIdx.x * 256 + threadIdx.x;
  if (i < NBIAS) {
    int j  = i % NTOK;
    int t  = i / NTOK;
    int ii = t % NTOK;
    int t2 = t / NTOK;
    int h  = t2 % HEADS;
    int w  = t2 / HEADS;
    int pos = pos_index[ii * NTOK + j];
    bias_exp[i] = f2bf(bias_table[(size_t)pos * (32 * HEADS) + w * HEADS + h]);
  } else if (i < NBIAS + NWQ) {
    int r = i - NBIAS;
    wq_b[r] = f2bf(qkv_w[r]);
  } else if (i < NBIAS + NWQ + NWP) {
    int r = i - NBIAS - NWQ;
    wp_b[r] = f2bf(proj_w[r]);
  }
}

// ---------------------------------------------------------------------------
// QKV GEMM: (138240 x 192) @ (576 x 192)^T + b.  Block = 4 waves, tile 64 tok
// x 576 cols; wave handles 64 tok x 144 cols (4x9 C frags). q gets *scale.
// Outputs q,k,v each laid out [(bw*6+h)][n][d] bf16 (contiguous 144x32 tiles).
// ---------------------------------------------------------------------------
__global__ __launch_bounds__(256, 1) void qkv_gemm(
    const float* __restrict__ x, const short* __restrict__ wq,
    const float* __restrict__ qbias,
    short* __restrict__ q, short* __restrict__ k, short* __restrict__ v)
{
  const int wave = threadIdx.x >> 6, lane = threadIdx.x & 63;
  const int m = lane & 15, g = lane >> 4;
  const int t0 = blockIdx.x * 64;
  const int c0 = wave * 144;

  f32x4 acc[4][9];
#pragma unroll
  for (int rt = 0; rt < 4; ++rt)
#pragma unroll
    for (int ct = 0; ct < 9; ++ct) acc[rt][ct] = (f32x4){0.f, 0.f, 0.f, 0.f};

  for (int kt = 0; kt < 6; ++kt) {
    const int kk = kt * 32 + g * 8;
    bf16x8 a[4];
#pragma unroll
    for (int rt = 0; rt < 4; ++rt) {
      const float* xp = x + (size_t)(t0 + rt * 16 + m) * DIM + kk;
      float4 f0 = *(const float4*)xp;
      float4 f1 = *(const float4*)(xp + 4);
      a[rt][0] = f2bf(f0.x); a[rt][1] = f2bf(f0.y); a[rt][2] = f2bf(f0.z); a[rt][3] = f2bf(f0.w);
      a[rt][4] = f2bf(f1.x); a[rt][5] = f2bf(f1.y); a[rt][6] = f2bf(f1.z); a[rt][7] = f2bf(f1.w);
    }
    bf16x8 b[9];
#pragma unroll
    for (int ct = 0; ct < 9; ++ct)
      b[ct] = *(const bf16x8*)(wq + (size_t)(c0 + ct * 16 + m) * DIM + kk);
#pragma unroll
    for (int rt = 0; rt < 4; ++rt)
#pragma unroll
      for (int ct = 0; ct < 9; ++ct)
        acc[rt][ct] = __builtin_amdgcn_mfma_f32_16x16x32_bf16(a[rt], b[ct], acc[rt][ct], 0, 0, 0);
  }

  const float scale = 0.17677669529663689f;   // 32^-0.5 folded into q
#pragma unroll
  for (int ct = 0; ct < 9; ++ct) {
    int co = c0 + ct * 16 + m;                // output channel 0..575
    int which = co / DIM;                     // 0=q 1=k 2=v
    int rem = co - which * DIM;
    int hh = rem >> 5, d = rem & 31;
    float bias = qbias[co];
    short* dst = which == 0 ? q : (which == 1 ? k : v);
    float sc = which == 0 ? scale : 1.0f;
#pragma unroll
    for (int rt = 0; rt < 4; ++rt) {
#pragma unroll
      for (int r = 0; r < 4; ++r) {
        int tok = t0 + rt * 16 + g * 4 + r;   // C layout: row=(lane>>4)*4+reg
        int bw = tok / NTOK;
        int n = tok - bw * NTOK;
        float val = (acc[rt][ct][r] + bias) * sc;
        dst[((size_t)(bw * HEADS + hh) * NTOK + n) * HD + d] = f2bf(val);
      }
    }
  }
}

// ---------------------------------------------------------------------------
// Attention: block = one (bw, h); 192 thr = 3 waves x 3 row-tiles of 16 rows.
// S = q@k^T (9 MFMA, K=32=hd), +bias+mask, softmax in-register via shfl over
// the 16-lane C-layout groups, P->LDS (bf16), O = P@V with V^T staged in LDS
// and K padded 144->160 (5 MFMA x 2 d-tiles).
// ---------------------------------------------------------------------------
__global__ __launch_bounds__(192, 3) void attn_kernel(
    const short* __restrict__ q, const short* __restrict__ k,
    const short* __restrict__ v, const short* __restrict__ bias_exp,
    const float* __restrict__ mask, short* __restrict__ aout)
{
  const int bwh = blockIdx.x;
  const int bw = bwh / HEADS;
  const int h  = bwh - bw * HEADS;
  const int w  = bw & 31;                    // window-type; lon = bw>>5

  __shared__ __align__(16) short vt[HD * PPITCH];       // v transposed [d][n]
  __shared__ __align__(16) short pl[3 * 16 * PPITCH];   // per-wave P tile

  const size_t base = (size_t)bwh * (NTOK * HD);
  const short* qb = q + base;
  const short* kb = k + base;
  const short* vb = v + base;

  // stage v -> vt[d][n]
  for (int i = threadIdx.x; i < (NTOK * HD) / 8; i += 192) {
    int n = i >> 2, dg = (i & 3) * 8;
    bf16x8 vv = *(const bf16x8*)(vb + n * HD + dg);
#pragma unroll
    for (int j = 0; j < 8; ++j) vt[(dg + j) * PPITCH + n] = vv[j];
  }
  // zero K-pad cols 144..160 of vt
  for (int i = threadIdx.x; i < 128; i += 192) {
    int d = i >> 2, c = 144 + (i & 3) * 4;
    *(short4v*)&vt[d * PPITCH + c] = (short4v){0, 0, 0, 0};
  }
  __syncthreads();

  const int wv = threadIdx.x >> 6;
  const int lane = threadIdx.x & 63;
  const int m = lane & 15, g = lane >> 4;
  short* myp = pl + wv * 16 * PPITCH;
  { // zero K-pad of own wave's P rows (own-region: no barrier needed)
    int r = lane >> 2, c = 144 + (lane & 3) * 4;
    *(short4v*)&myp[r * PPITCH + c] = (short4v){0, 0, 0, 0};
  }

  const short* bp = bias_exp + (size_t)(w * HEADS + h) * (NTOK * NTOK);
  const float* mp = mask + (size_t)bw * (NTOK * NTOK);   // mask[lon][w] == flat bw

  for (int rt = wv * 3; rt < wv * 3 + 3; ++rt) {
    const int i0 = rt * 16;
    bf16x8 aq = *(const bf16x8*)(qb + (size_t)(i0 + m) * HD + g * 8);
    f32x4 s[9];
#pragma unroll
    for (int jt = 0; jt < 9; ++jt) {
      bf16x8 bk = *(const bf16x8*)(kb + (size_t)(jt * 16 + m) * HD + g * 8);
      s[jt] = __builtin_amdgcn_mfma_f32_16x16x32_bf16(aq, bk, (f32x4){0.f, 0.f, 0.f, 0.f}, 0, 0, 0);
    }
    // bias + mask + row max (C layout: col=lane&15, row=(lane>>4)*4+reg)
    float mx[4] = {-3e38f, -3e38f, -3e38f, -3e38f};
#pragma unroll
    for (int jt = 0; jt < 9; ++jt) {
#pragma unroll
      for (int r = 0; r < 4; ++r) {
        int row = i0 + g * 4 + r, col = jt * 16 + m;
        float val = s[jt][r] + bf2f(bp[row * NTOK + col]) + mp[row * NTOK + col];
        s[jt][r] = val;
        mx[r] = fmaxf(mx[r], val);
      }
    }
#pragma unroll
    for (int r = 0; r < 4; ++r) {
      mx[r] = fmaxf(mx[r], __shfl_xor(mx[r], 1, 64));
      mx[r] = fmaxf(mx[r], __shfl_xor(mx[r], 2, 64));
      mx[r] = fmaxf(mx[r], __shfl_xor(mx[r], 4, 64));
      mx[r] = fmaxf(mx[r], __shfl_xor(mx[r], 8, 64));
    }
    float sum[4] = {0.f, 0.f, 0.f, 0.f};
#pragma unroll
    for (int jt = 0; jt < 9; ++jt) {
#pragma unroll
      for (int r = 0; r < 4; ++r) {
        float e = __expf(s[jt][r] - mx[r]);
        s[jt][r] = e;
        sum[r] += e;
      }
    }
#pragma unroll
    for (int r = 0; r < 4; ++r) {
      sum[r] += __shfl_xor(sum[r], 1, 64);
      sum[r] += __shfl_xor(sum[r], 2, 64);
      sum[r] += __shfl_xor(sum[r], 4, 64);
      sum[r] += __shfl_xor(sum[r], 8, 64);
    }
    // P (unnormalized) -> LDS bf16; same-wave write->read, compiler orders via lgkmcnt
#pragma unroll
    for (int jt = 0; jt < 9; ++jt)
#pragma unroll
      for (int r = 0; r < 4; ++r)
        myp[(g * 4 + r) * PPITCH + jt * 16 + m] = f2bf(s[jt][r]);

    // O = P @ V : A=P[m][k], B=vt[d][k]; K = 160 (zero-padded)
    f32x4 o0 = (f32x4){0.f, 0.f, 0.f, 0.f};
    f32x4 o1 = (f32x4){0.f, 0.f, 0.f, 0.f};
#pragma unroll
    for (int kt = 0; kt < 5; ++kt) {
      bf16x8 ap = *(const bf16x8*)(myp + m * PPITCH + kt * 32 + g * 8);
      bf16x8 b0 = *(const bf16x8*)(vt + m * PPITCH + kt * 32 + g * 8);
      bf16x8 b1 = *(const bf16x8*)(vt + (16 + m) * PPITCH + kt * 32 + g * 8);
      o0 = __builtin_amdgcn_mfma_f32_16x16x32_bf16(ap, b0, o0, 0, 0, 0);
      o1 = __builtin_amdgcn_mfma_f32_16x16x32_bf16(ap, b1, o1, 0, 0, 0);
    }
    size_t ob = ((size_t)bw * NTOK + i0 + g * 4) * DIM + h * HD + m;
#pragma unroll
    for (int r = 0; r < 4; ++r) {
      float rs = 1.0f / sum[r];
      aout[ob + (size_t)r * DIM]      = f2bf(o0[r] * rs);
      aout[ob + (size_t)r * DIM + 16] = f2bf(o1[r] * rs);
    }
  }
}

// ---------------------------------------------------------------------------
// Proj GEMM: (138240 x 192 bf16) @ (192 x 192)^T + b -> fp32 d_out.
// Block = 4 waves: 2 token-groups x 2 col-groups; wave = 64 tok x 96 cols.
// ---------------------------------------------------------------------------
__global__ __launch_bounds__(256, 1) void proj_gemm(
    const short* __restrict__ ain, const short* __restrict__ pw,
    const float* __restrict__ pb, float* __restrict__ out)
{
  const int wave = threadIdx.x >> 6, lane = threadIdx.x & 63;
  const int m = lane & 15, g = lane >> 4;
  const int t0 = blockIdx.x * 128 + (wave >> 1) * 64;
  const int c0 = (wave & 1) * 96;

  f32x4 acc[4][6];
#pragma unroll
  for (int rt = 0; rt < 4; ++rt)
#pragma unroll
    for (int ct = 0; ct < 6; ++ct) acc[rt][ct] = (f32x4){0.f, 0.f, 0.f, 0.f};

  for (int kt = 0; kt < 6; ++kt) {
    const int kk = kt * 32 + g * 8;
    bf16x8 a[4];
#pragma unroll
    for (int rt = 0; rt < 4; ++rt)
      a[rt] = *(const bf16x8*)(ain + (size_t)(t0 + rt * 16 + m) * DIM + kk);
    bf16x8 b[6];
#pragma unroll
    for (int ct = 0; ct < 6; ++ct)
      b[ct] = *(const bf16x8*)(pw + (size_t)(c0 + ct * 16 + m) * DIM + kk);
#pragma unroll
    for (int rt = 0; rt < 4; ++rt)
#pragma unroll
      for (int ct = 0; ct < 6; ++ct)
        acc[rt][ct] = __builtin_amdgcn_mfma_f32_16x16x32_bf16(a[rt], b[ct], acc[rt][ct], 0, 0, 0);
  }

#pragma unroll
  for (int ct = 0; ct < 6; ++ct) {
    int co = c0 + ct * 16 + m;
    float bias = pb[co];
#pragma unroll
    for (int rt = 0; rt < 4; ++rt)
#pragma unroll
      for (int r = 0; r < 4; ++r)
        out[(size_t)(t0 + rt * 16 + g * 4 + r) * DIM + co] = acc[rt][ct][r] + bias;
  }
}

// ---------------------------------------------------------------------------
extern "C" void kernel_launch(void* const* d_in, const int* in_sizes, int n_in,
                              void* d_out, int out_size, void* d_ws, size_t ws_size,
                              hipStream_t stream) {
  const float* x          = (const float*)d_in[0];
  const float* mask       = (const float*)d_in[1];
  const float* qkv_w      = (const float*)d_in[2];
  const float* qkv_b      = (const float*)d_in[3];
  const float* proj_w     = (const float*)d_in[4];
  const float* proj_b     = (const float*)d_in[5];
  const float* bias_table = (const float*)d_in[6];
  const int*   pos_index  = (const int*)d_in[7];
  float* out = (float*)d_out;

  // workspace carve (all 16B-aligned): q,k,v,aout bf16 + weights + bias_exp
  const size_t NELEM = (size_t)TOKENS * DIM;   // 26,542,080
  short* qv   = (short*)d_ws;
  short* kv   = qv + NELEM;
  short* vv   = kv + NELEM;
  short* aout = vv + NELEM;
  short* wqb  = aout + NELEM;
  short* wpb  = wqb + NWQ;
  short* bex  = wpb + NWP;
  // total = 4*NELEM + NWQ + NWP + NBIAS shorts = 220,594,176 bytes

  prep_kernel<<<(NBIAS + NWQ + NWP + 255) / 256, 256, 0, stream>>>(
      qkv_w, proj_w, bias_table, pos_index, wqb, wpb, bex);
  qkv_gemm<<<TOKENS / 64, 256, 0, stream>>>(x, wqb, qkv_b, qv, kv, vv);
  attn_kernel<<<NBWH, 192, 0, stream>>>(qv, kv, vv, bex, mask, aout);
  proj_gemm<<<TOKENS / 128, 256, 0, stream>>>(aout, wpb, proj_b, out);
}

// Round 2
// 599.402 us; speedup vs baseline: 1.0038x; 1.0038x over previous
//
#include <hip/hip_runtime.h>
#include <hip/hip_bf16.h>

// EarthAttention3D (Pangu): B_=30, nW=32, N=144, C=192, H=6, hd=32
#define DIM    192
#define HEADS  6
#define HD     32
#define NTOK   144                  // tokens per window
#define NWIN   960                  // 30 lon * 32 window-types
#define NBWH   (NWIN * HEADS)       // 5760
#define TOKENS (NWIN * NTOK)        // 138240
#define PPITCH 168                  // LDS row pitch in halves

typedef __attribute__((ext_vector_type(8))) short bf16x8;   // 8 bf16 in 4 VGPRs (MFMA A/B frag)
typedef __attribute__((ext_vector_type(4))) float f32x4;    // MFMA C/D frag
typedef __attribute__((ext_vector_type(4))) short short4v;

static __device__ __forceinline__ short f2bf(float f) {
  __hip_bfloat16 h = __float2bfloat16(f);      // RTN
  return __builtin_bit_cast(short, h);
}
static __device__ __forceinline__ float bf2f(short s) {
  unsigned u = ((unsigned)(unsigned short)s) << 16;
  return __builtin_bit_cast(float, u);
}

// ---------------------------------------------------------------------------
// prep: cast weights to bf16 + expand positional bias gather once.
// bias_exp[w][h][i][j] = bias_table[pos_index[i][j]][w][h]   (bf16)
// Vectorized: each thread produces one 8-element (16 B) chunk.
// ---------------------------------------------------------------------------
#define NBIAS (32 * HEADS * NTOK * NTOK)   // 3,981,312
#define NWQ   (3 * DIM * DIM)              // 110,592
#define NWP   (DIM * DIM)                  // 36,864
#define NB8   (NBIAS / 8)                  // 497,664
#define NWQ8  (NWQ / 8)                    // 13,824
#define NWP8  (NWP / 8)                    // 4,608

__global__ __launch_bounds__(256) void prep_kernel(
    const float* __restrict__ qkv_w, const float* __restrict__ proj_w,
    const float* __restrict__ bias_table, const int* __restrict__ pos_index,
    short* __restrict__ wq_b, short* __restrict__ wp_b, short* __restrict__ bias_exp)
{
  int i = blockIdx.x * 256 + threadIdx.x;
  if (i < NB8) {
    int flat = i * 8;
    int j0 = flat % NTOK;           // 144 = 18*8, chunks never cross a j-row
    int t  = flat / NTOK;
    int ii = t % NTOK;
    int t2 = t / NTOK;
    int h  = t2 % HEADS;
    int w  = t2 / HEADS;
    const int* pr = pos_index + ii * NTOK + j0;
    bf16x8 o;
#pragma unroll
    for (int jj = 0; jj < 8; ++jj)
      o[jj] = f2bf(bias_table[(size_t)pr[jj] * (32 * HEADS) + w * HEADS + h]);
    *(bf16x8*)(bias_exp + flat) = o;
  } else if (i < NB8 + NWQ8) {
    int flat = (i - NB8) * 8;
    float4 f0 = *(const float4*)(qkv_w + flat);
    float4 f1 = *(const float4*)(qkv_w + flat + 4);
    bf16x8 o;
    o[0]=f2bf(f0.x); o[1]=f2bf(f0.y); o[2]=f2bf(f0.z); o[3]=f2bf(f0.w);
    o[4]=f2bf(f1.x); o[5]=f2bf(f1.y); o[6]=f2bf(f1.z); o[7]=f2bf(f1.w);
    *(bf16x8*)(wq_b + flat) = o;
  } else if (i < NB8 + NWQ8 + NWP8) {
    int flat = (i - NB8 - NWQ8) * 8;
    float4 f0 = *(const float4*)(proj_w + flat);
    float4 f1 = *(const float4*)(proj_w + flat + 4);
    bf16x8 o;
    o[0]=f2bf(f0.x); o[1]=f2bf(f0.y); o[2]=f2bf(f0.z); o[3]=f2bf(f0.w);
    o[4]=f2bf(f1.x); o[5]=f2bf(f1.y); o[6]=f2bf(f1.z); o[7]=f2bf(f1.w);
    *(bf16x8*)(wp_b + flat) = o;
  }
}

// ---------------------------------------------------------------------------
// QKV GEMM: (138240 x 192) @ (576 x 192)^T + b.
// Block = 4 waves = 128 tokens; wave = 32 tok x 144 cols (2x9 C frags = 72
// AGPR -> ~142 regs total -> 3 waves/SIMD, vs R1's 292 -> 1 wave/SIMD).
// Grid (4 colblk, 1080 rowblk): col-blocks sharing x rows dispatch adjacently.
// ---------------------------------------------------------------------------
__global__ __launch_bounds__(256, 2) void qkv_gemm(
    const float* __restrict__ x, const short* __restrict__ wq,
    const float* __restrict__ qbias,
    short* __restrict__ q, short* __restrict__ k, short* __restrict__ v)
{
  const int wave = threadIdx.x >> 6, lane = threadIdx.x & 63;
  const int m = lane & 15, g = lane >> 4;
  const int t0 = blockIdx.y * 128 + wave * 32;
  const int c0 = blockIdx.x * 144;

  f32x4 acc[2][9];
#pragma unroll
  for (int rt = 0; rt < 2; ++rt)
#pragma unroll
    for (int ct = 0; ct < 9; ++ct) acc[rt][ct] = (f32x4){0.f, 0.f, 0.f, 0.f};

  for (int ks = 0; ks < 6; ++ks) {
    const int kk = ks * 32 + g * 8;
    bf16x8 a[2];
#pragma unroll
    for (int rt = 0; rt < 2; ++rt) {
      const float* xp = x + (size_t)(t0 + rt * 16 + m) * DIM + kk;
      float4 f0 = *(const float4*)xp;
      float4 f1 = *(const float4*)(xp + 4);
      a[rt][0] = f2bf(f0.x); a[rt][1] = f2bf(f0.y); a[rt][2] = f2bf(f0.z); a[rt][3] = f2bf(f0.w);
      a[rt][4] = f2bf(f1.x); a[rt][5] = f2bf(f1.y); a[rt][6] = f2bf(f1.z); a[rt][7] = f2bf(f1.w);
    }
    bf16x8 b[9];
#pragma unroll
    for (int ct = 0; ct < 9; ++ct)
      b[ct] = *(const bf16x8*)(wq + (size_t)(c0 + ct * 16 + m) * DIM + kk);
#pragma unroll
    for (int rt = 0; rt < 2; ++rt)
#pragma unroll
      for (int ct = 0; ct < 9; ++ct)
        acc[rt][ct] = __builtin_amdgcn_mfma_f32_16x16x32_bf16(a[rt], b[ct], acc[rt][ct], 0, 0, 0);
  }

  const float scale = 0.17677669529663689f;   // 32^-0.5 folded into q
#pragma unroll
  for (int ct = 0; ct < 9; ++ct) {
    int co = c0 + ct * 16 + m;                // output channel 0..575
    int which = co / DIM;                     // 0=q 1=k 2=v
    int rem = co - which * DIM;
    int hh = rem >> 5, d = rem & 31;
    float bias = qbias[co];
    short* dst = which == 0 ? q : (which == 1 ? k : v);
    float sc = which == 0 ? scale : 1.0f;
#pragma unroll
    for (int rt = 0; rt < 2; ++rt) {
#pragma unroll
      for (int r = 0; r < 4; ++r) {
        int tok = t0 + rt * 16 + g * 4 + r;   // C layout: row=(lane>>4)*4+reg
        int bw = tok / NTOK;
        int n = tok - bw * NTOK;
        float val = (acc[rt][ct][r] + bias) * sc;
        dst[((size_t)(bw * HEADS + hh) * NTOK + n) * HD + d] = f2bf(val);
      }
    }
  }
}

// ---------------------------------------------------------------------------
// Attention: block = one (bw, h); 192 thr = 3 waves x 3 row-tiles of 16 rows.
// ---------------------------------------------------------------------------
__global__ __launch_bounds__(192, 3) void attn_kernel(
    const short* __restrict__ q, const short* __restrict__ k,
    const short* __restrict__ v, const short* __restrict__ bias_exp,
    const float* __restrict__ mask, short* __restrict__ aout)
{
  const int bwh = blockIdx.x;
  const int bw = bwh / HEADS;
  const int h  = bwh - bw * HEADS;
  const int w  = bw & 31;                    // window-type; lon = bw>>5

  __shared__ __align__(16) short vt[HD * PPITCH];       // v transposed [d][n]
  __shared__ __align__(16) short pl[3 * 16 * PPITCH];   // per-wave P tile

  const size_t base = (size_t)bwh * (NTOK * HD);
  const short* qb = q + base;
  const short* kb = k + base;
  const short* vb = v + base;

  // stage v -> vt[d][n]
  for (int i = threadIdx.x; i < (NTOK * HD) / 8; i += 192) {
    int n = i >> 2, dg = (i & 3) * 8;
    bf16x8 vv = *(const bf16x8*)(vb + n * HD + dg);
#pragma unroll
    for (int j = 0; j < 8; ++j) vt[(dg + j) * PPITCH + n] = vv[j];
  }
  // zero K-pad cols 144..160 of vt
  for (int i = threadIdx.x; i < 128; i += 192) {
    int d = i >> 2, c = 144 + (i & 3) * 4;
    *(short4v*)&vt[d * PPITCH + c] = (short4v){0, 0, 0, 0};
  }
  __syncthreads();

  const int wv = threadIdx.x >> 6;
  const int lane = threadIdx.x & 63;
  const int m = lane & 15, g = lane >> 4;
  short* myp = pl + wv * 16 * PPITCH;
  { // zero K-pad of own wave's P rows (own-region: no barrier needed)
    int r = lane >> 2, c = 144 + (lane & 3) * 4;
    *(short4v*)&myp[r * PPITCH + c] = (short4v){0, 0, 0, 0};
  }

  const short* bp = bias_exp + (size_t)(w * HEADS + h) * (NTOK * NTOK);
  const float* mp = mask + (size_t)bw * (NTOK * NTOK);   // mask[lon][w] == flat bw

  for (int rt = wv * 3; rt < wv * 3 + 3; ++rt) {
    const int i0 = rt * 16;
    bf16x8 aq = *(const bf16x8*)(qb + (size_t)(i0 + m) * HD + g * 8);
    f32x4 s[9];
#pragma unroll
    for (int jt = 0; jt < 9; ++jt) {
      bf16x8 bk = *(const bf16x8*)(kb + (size_t)(jt * 16 + m) * HD + g * 8);
      s[jt] = __builtin_amdgcn_mfma_f32_16x16x32_bf16(aq, bk, (f32x4){0.f, 0.f, 0.f, 0.f}, 0, 0, 0);
    }
    // bias + mask + row max (C layout: col=lane&15, row=(lane>>4)*4+reg)
    float mx[4] = {-3e38f, -3e38f, -3e38f, -3e38f};
#pragma unroll
    for (int jt = 0; jt < 9; ++jt) {
#pragma unroll
      for (int r = 0; r < 4; ++r) {
        int row = i0 + g * 4 + r, col = jt * 16 + m;
        float val = s[jt][r] + bf2f(bp[row * NTOK + col]) + mp[row * NTOK + col];
        s[jt][r] = val;
        mx[r] = fmaxf(mx[r], val);
      }
    }
#pragma unroll
    for (int r = 0; r < 4; ++r) {
      mx[r] = fmaxf(mx[r], __shfl_xor(mx[r], 1, 64));
      mx[r] = fmaxf(mx[r], __shfl_xor(mx[r], 2, 64));
      mx[r] = fmaxf(mx[r], __shfl_xor(mx[r], 4, 64));
      mx[r] = fmaxf(mx[r], __shfl_xor(mx[r], 8, 64));
    }
    float sum[4] = {0.f, 0.f, 0.f, 0.f};
#pragma unroll
    for (int jt = 0; jt < 9; ++jt) {
#pragma unroll
      for (int r = 0; r < 4; ++r) {
        float e = __expf(s[jt][r] - mx[r]);
        s[jt][r] = e;
        sum[r] += e;
      }
    }
#pragma unroll
    for (int r = 0; r < 4; ++r) {
      sum[r] += __shfl_xor(sum[r], 1, 64);
      sum[r] += __shfl_xor(sum[r], 2, 64);
      sum[r] += __shfl_xor(sum[r], 4, 64);
      sum[r] += __shfl_xor(sum[r], 8, 64);
    }
    // P (unnormalized) -> LDS bf16; same-wave write->read, compiler orders via lgkmcnt
#pragma unroll
    for (int jt = 0; jt < 9; ++jt)
#pragma unroll
      for (int r = 0; r < 4; ++r)
        myp[(g * 4 + r) * PPITCH + jt * 16 + m] = f2bf(s[jt][r]);

    // O = P @ V : A=P[m][k], B=vt[d][k]; K = 160 (zero-padded)
    f32x4 o0 = (f32x4){0.f, 0.f, 0.f, 0.f};
    f32x4 o1 = (f32x4){0.f, 0.f, 0.f, 0.f};
#pragma unroll
    for (int kt = 0; kt < 5; ++kt) {
      bf16x8 ap = *(const bf16x8*)(myp + m * PPITCH + kt * 32 + g * 8);
      bf16x8 b0 = *(const bf16x8*)(vt + m * PPITCH + kt * 32 + g * 8);
      bf16x8 b1 = *(const bf16x8*)(vt + (16 + m) * PPITCH + kt * 32 + g * 8);
      o0 = __builtin_amdgcn_mfma_f32_16x16x32_bf16(ap, b0, o0, 0, 0, 0);
      o1 = __builtin_amdgcn_mfma_f32_16x16x32_bf16(ap, b1, o1, 0, 0, 0);
    }
    size_t ob = ((size_t)bw * NTOK + i0 + g * 4) * DIM + h * HD + m;
#pragma unroll
    for (int r = 0; r < 4; ++r) {
      float rs = 1.0f / sum[r];
      aout[ob + (size_t)r * DIM]      = f2bf(o0[r] * rs);
      aout[ob + (size_t)r * DIM + 16] = f2bf(o1[r] * rs);
    }
  }
}

// ---------------------------------------------------------------------------
// Proj GEMM: (138240 x 192 bf16) @ (192 x 192)^T + b -> fp32 d_out.
// Block = 4 waves = 128 tok; wave = 32 tok x 96 cols (2x6 frags = 48 AGPR).
// Grid (2 colblk, 1080 rowblk).
// ---------------------------------------------------------------------------
__global__ __launch_bounds__(256, 2) void proj_gemm(
    const short* __restrict__ ain, const short* __restrict__ pw,
    const float* __restrict__ pb, float* __restrict__ out)
{
  const int wave = threadIdx.x >> 6, lane = threadIdx.x & 63;
  const int m = lane & 15, g = lane >> 4;
  const int t0 = blockIdx.y * 128 + wave * 32;
  const int c0 = blockIdx.x * 96;

  f32x4 acc[2][6];
#pragma unroll
  for (int rt = 0; rt < 2; ++rt)
#pragma unroll
    for (int ct = 0; ct < 6; ++ct) acc[rt][ct] = (f32x4){0.f, 0.f, 0.f, 0.f};

  for (int ks = 0; ks < 6; ++ks) {
    const int kk = ks * 32 + g * 8;
    bf16x8 a[2];
#pragma unroll
    for (int rt = 0; rt < 2; ++rt)
      a[rt] = *(const bf16x8*)(ain + (size_t)(t0 + rt * 16 + m) * DIM + kk);
    bf16x8 b[6];
#pragma unroll
    for (int ct = 0; ct < 6; ++ct)
      b[ct] = *(const bf16x8*)(pw + (size_t)(c0 + ct * 16 + m) * DIM + kk);
#pragma unroll
    for (int rt = 0; rt < 2; ++rt)
#pragma unroll
      for (int ct = 0; ct < 6; ++ct)
        acc[rt][ct] = __builtin_amdgcn_mfma_f32_16x16x32_bf16(a[rt], b[ct], acc[rt][ct], 0, 0, 0);
  }

#pragma unroll
  for (int ct = 0; ct < 6; ++ct) {
    int co = c0 + ct * 16 + m;
    float bias = pb[co];
#pragma unroll
    for (int rt = 0; rt < 2; ++rt)
#pragma unroll
      for (int r = 0; r < 4; ++r)
        out[(size_t)(t0 + rt * 16 + g * 4 + r) * DIM + co] = acc[rt][ct][r] + bias;
  }
}

// ---------------------------------------------------------------------------
extern "C" void kernel_launch(void* const* d_in, const int* in_sizes, int n_in,
                              void* d_out, int out_size, void* d_ws, size_t ws_size,
                              hipStream_t stream) {
  const float* x          = (const float*)d_in[0];
  const float* mask       = (const float*)d_in[1];
  const float* qkv_w      = (const float*)d_in[2];
  const float* qkv_b      = (const float*)d_in[3];
  const float* proj_w     = (const float*)d_in[4];
  const float* proj_b     = (const float*)d_in[5];
  const float* bias_table = (const float*)d_in[6];
  const int*   pos_index  = (const int*)d_in[7];
  float* out = (float*)d_out;

  // workspace carve (all 16B-aligned): q,k,v,aout bf16 + weights + bias_exp
  const size_t NELEM = (size_t)TOKENS * DIM;   // 26,542,080
  short* qv   = (short*)d_ws;
  short* kv   = qv + NELEM;
  short* vv   = kv + NELEM;
  short* aout = vv + NELEM;
  short* wqb  = aout + NELEM;
  short* wpb  = wqb + NWQ;
  short* bex  = wpb + NWP;

  prep_kernel<<<(NB8 + NWQ8 + NWP8 + 255) / 256, 256, 0, stream>>>(
      qkv_w, proj_w, bias_table, pos_index, wqb, wpb, bex);
  qkv_gemm<<<dim3(4, 1080), 256, 0, stream>>>(x, wqb, qkv_b, qv, kv, vv);
  attn_kernel<<<NBWH, 192, 0, stream>>>(qv, kv, vv, bex, mask, aout);
  proj_gemm<<<dim3(2, 1080), 256, 0, stream>>>(aout, wpb, proj_b, out);
}

// Round 3
// 585.473 us; speedup vs baseline: 1.0277x; 1.0238x over previous
//
#include <hip/hip_runtime.h>
#include <hip/hip_bf16.h>

// EarthAttention3D (Pangu): B_=30, nW=32, N=144, C=192, H=6, hd=32
#define DIM    192
#define HEADS  6
#define HD     32
#define NTOK   144                  // tokens per window
#define NWIN   960                  // 30 lon * 32 window-types
#define NBWH   (NWIN * HEADS)       // 5760
#define TOKENS (NWIN * NTOK)        // 138240
#define PPITCH 168                  // attn LDS row pitch (halves)
#define XPITCH 200                  // gemm LDS x-tile pitch (halves): 100 dwords %32=4 -> 2-way max (free)

typedef __attribute__((ext_vector_type(8))) short bf16x8;   // MFMA A/B frag (4 VGPRs)
typedef __attribute__((ext_vector_type(4))) float f32x4;    // MFMA C/D frag
typedef __attribute__((ext_vector_type(4))) short short4v;  // 8 B vector store

static __device__ __forceinline__ short f2bf(float f) {
  __hip_bfloat16 h = __float2bfloat16(f);      // RTN
  return __builtin_bit_cast(short, h);
}
static __device__ __forceinline__ float bf2f(short s) {
  unsigned u = ((unsigned)(unsigned short)s) << 16;
  return __builtin_bit_cast(float, u);
}

// ---------------------------------------------------------------------------
// prep: bf16 weight casts + TRANSPOSED bias/mask expansion.
// biasT[w][h][key][query], maskT[bw][key][query]  (bf16) — so attn can load
// 4 consecutive query rows per lane as one short4.
// ---------------------------------------------------------------------------
#define NBIAS (32 * HEADS * NTOK * NTOK)   // 3,981,312
#define NMASK (NWIN * NTOK * NTOK)         // 19,906,560
#define NWQ   (3 * DIM * DIM)              // 110,592
#define NWP   (DIM * DIM)                  // 36,864
#define NB8   (NBIAS / 8)
#define NM8   (NMASK / 8)
#define NWQ8  (NWQ / 8)
#define NWP8  (NWP / 8)

__global__ __launch_bounds__(256) void prep_kernel(
    const float* __restrict__ qkv_w, const float* __restrict__ proj_w,
    const float* __restrict__ bias_table, const int* __restrict__ pos_index,
    const float* __restrict__ mask,
    short* __restrict__ wq_b, short* __restrict__ wp_b,
    short* __restrict__ biasT, short* __restrict__ maskT)
{
  int i = blockIdx.x * 256 + threadIdx.x;
  if (i < NB8) {
    // one thread: 8 consecutive queries at fixed (w,h,key)
    int flat = i * 8;
    int q0 = flat % NTOK;
    int t  = flat / NTOK;
    int kk = t % NTOK;
    int t2 = t / NTOK;
    int h  = t2 % HEADS;
    int w  = t2 / HEADS;
    bf16x8 o;
#pragma unroll
    for (int jj = 0; jj < 8; ++jj) {
      int pos = pos_index[(q0 + jj) * NTOK + kk];
      o[jj] = f2bf(bias_table[(size_t)pos * (32 * HEADS) + w * HEADS + h]);
    }
    *(bf16x8*)(biasT + (size_t)((w * HEADS + h) * NTOK + kk) * NTOK + q0) = o;
  } else if (i < NB8 + NM8) {
    int flat = (i - NB8) * 8;
    int q0 = flat % NTOK;
    int t  = flat / NTOK;
    int kk = t % NTOK;
    int bw = t / NTOK;
    bf16x8 o;
#pragma unroll
    for (int jj = 0; jj < 8; ++jj)
      o[jj] = f2bf(mask[((size_t)bw * NTOK + q0 + jj) * NTOK + kk]);
    *(bf16x8*)(maskT + ((size_t)bw * NTOK + kk) * NTOK + q0) = o;
  } else if (i < NB8 + NM8 + NWQ8) {
    int flat = (i - NB8 - NM8) * 8;
    float4 f0 = *(const float4*)(qkv_w + flat);
    float4 f1 = *(const float4*)(qkv_w + flat + 4);
    bf16x8 o;
    o[0]=f2bf(f0.x); o[1]=f2bf(f0.y); o[2]=f2bf(f0.z); o[3]=f2bf(f0.w);
    o[4]=f2bf(f1.x); o[5]=f2bf(f1.y); o[6]=f2bf(f1.z); o[7]=f2bf(f1.w);
    *(bf16x8*)(wq_b + flat) = o;
  } else if (i < NB8 + NM8 + NWQ8 + NWP8) {
    int flat = (i - NB8 - NM8 - NWQ8) * 8;
    float4 f0 = *(const float4*)(proj_w + flat);
    float4 f1 = *(const float4*)(proj_w + flat + 4);
    bf16x8 o;
    o[0]=f2bf(f0.x); o[1]=f2bf(f0.y); o[2]=f2bf(f0.z); o[3]=f2bf(f0.w);
    o[4]=f2bf(f1.x); o[5]=f2bf(f1.y); o[6]=f2bf(f1.z); o[7]=f2bf(f1.w);
    *(bf16x8*)(wp_b + flat) = o;
  }
}

// ---------------------------------------------------------------------------
// QKV GEMM, operand-swapped: D[channel][token] tiles. Block = 32 tokens x 576
// channels; x tile staged in LDS once (bf16), 4 waves each do 144 channels.
// Lane holds 4 consecutive channels x 1 token -> short4 8B stores (18/lane
// vs 72 scalar 2B in R2).
// ---------------------------------------------------------------------------
__global__ __launch_bounds__(256, 2) void qkv_gemm(
    const float* __restrict__ x, const short* __restrict__ wq,
    const float* __restrict__ qbias,
    short* __restrict__ q, short* __restrict__ k, short* __restrict__ v)
{
  __shared__ __align__(16) short xs[32 * XPITCH];
  const int t0 = blockIdx.x * 32;

  { // stage x tile (32 tok x 192 ch fp32 -> bf16 LDS)
    const int row = threadIdx.x >> 3;        // 0..31
    const int cg  = threadIdx.x & 7;         // 24 floats each
    const float* xp = x + (size_t)(t0 + row) * DIM + cg * 24;
    short* dstp = xs + row * XPITCH + cg * 24;
#pragma unroll
    for (int i = 0; i < 3; ++i) {
      float4 f0 = *(const float4*)(xp + i * 8);
      float4 f1 = *(const float4*)(xp + i * 8 + 4);
      bf16x8 o;
      o[0]=f2bf(f0.x); o[1]=f2bf(f0.y); o[2]=f2bf(f0.z); o[3]=f2bf(f0.w);
      o[4]=f2bf(f1.x); o[5]=f2bf(f1.y); o[6]=f2bf(f1.z); o[7]=f2bf(f1.w);
      *(bf16x8*)(dstp + i * 8) = o;
    }
  }
  __syncthreads();

  const int wave = threadIdx.x >> 6, lane = threadIdx.x & 63;
  const int m = lane & 15, g = lane >> 4;
  const int c0w = wave * 144;

  f32x4 acc[9][2];
#pragma unroll
  for (int ct = 0; ct < 9; ++ct)
#pragma unroll
    for (int rt = 0; rt < 2; ++rt) acc[ct][rt] = (f32x4){0.f, 0.f, 0.f, 0.f};

  for (int ks = 0; ks < 6; ++ks) {
    const int kk = ks * 32 + g * 8;
    bf16x8 b0 = *(const bf16x8*)(xs + m * XPITCH + kk);
    bf16x8 b1 = *(const bf16x8*)(xs + (16 + m) * XPITCH + kk);
#pragma unroll
    for (int ct = 0; ct < 9; ++ct) {
      bf16x8 a = *(const bf16x8*)(wq + (size_t)(c0w + ct * 16 + m) * DIM + kk);
      acc[ct][0] = __builtin_amdgcn_mfma_f32_16x16x32_bf16(a, b0, acc[ct][0], 0, 0, 0);
      acc[ct][1] = __builtin_amdgcn_mfma_f32_16x16x32_bf16(a, b1, acc[ct][1], 0, 0, 0);
    }
  }

  const float scale = 0.17677669529663689f;   // 32^-0.5 folded into q
#pragma unroll
  for (int ct = 0; ct < 9; ++ct) {
    int co0 = c0w + ct * 16 + g * 4;          // 4 consecutive output channels
    int which = co0 / DIM;                    // 0=q 1=k 2=v (16-tiles never straddle)
    int rem = co0 - which * DIM;
    int hh = rem >> 5, d0 = rem & 31;
    float4 b4 = *(const float4*)(qbias + co0);
    short* dst = which == 0 ? q : (which == 1 ? k : v);
    float sc = which == 0 ? scale : 1.0f;
#pragma unroll
    for (int rt = 0; rt < 2; ++rt) {
      int tok = t0 + rt * 16 + m;
      int bw = tok / NTOK, n = tok - bw * NTOK;
      short4v s;
      s[0] = f2bf((acc[ct][rt][0] + b4.x) * sc);
      s[1] = f2bf((acc[ct][rt][1] + b4.y) * sc);
      s[2] = f2bf((acc[ct][rt][2] + b4.z) * sc);
      s[3] = f2bf((acc[ct][rt][3] + b4.w) * sc);
      *(short4v*)(dst + ((size_t)(bw * HEADS + hh) * NTOK + n) * HD + d0) = s;
    }
  }
}

// ---------------------------------------------------------------------------
// Attention: block = one (bw, h); 192 thr = 3 waves x 3 row-tiles of 16 rows.
// biasT/maskT give short4 loads; PV operand-swapped -> short4 stores; P is
// normalized before the PV matmul (so no per-column rescale needed after).
// ---------------------------------------------------------------------------
__global__ __launch_bounds__(192, 3) void attn_kernel(
    const short* __restrict__ q, const short* __restrict__ k,
    const short* __restrict__ v, const short* __restrict__ biasT,
    const short* __restrict__ maskT, short* __restrict__ aout)
{
  const int bwh = blockIdx.x;
  const int bw = bwh / HEADS;
  const int h  = bwh - bw * HEADS;
  const int w  = bw & 31;                    // window-type; lon = bw>>5

  __shared__ __align__(16) short vt[HD * PPITCH];       // v transposed [d][n]
  __shared__ __align__(16) short pl[3 * 16 * PPITCH];   // per-wave P tile

  const size_t base = (size_t)bwh * (NTOK * HD);
  const short* qb = q + base;
  const short* kb = k + base;
  const short* vb = v + base;

  // stage v -> vt[d][n]
  for (int i = threadIdx.x; i < (NTOK * HD) / 8; i += 192) {
    int n = i >> 2, dg = (i & 3) * 8;
    bf16x8 vv = *(const bf16x8*)(vb + n * HD + dg);
#pragma unroll
    for (int j = 0; j < 8; ++j) vt[(dg + j) * PPITCH + n] = vv[j];
  }
  // zero K-pad cols 144..160 of vt
  for (int i = threadIdx.x; i < 128; i += 192) {
    int d = i >> 2, c = 144 + (i & 3) * 4;
    *(short4v*)&vt[d * PPITCH + c] = (short4v){0, 0, 0, 0};
  }
  __syncthreads();

  const int wv = threadIdx.x >> 6;
  const int lane = threadIdx.x & 63;
  const int m = lane & 15, g = lane >> 4;
  short* myp = pl + wv * 16 * PPITCH;
  { // zero K-pad of own wave's P rows
    int r = lane >> 2, c = 144 + (lane & 3) * 4;
    *(short4v*)&myp[r * PPITCH + c] = (short4v){0, 0, 0, 0};
  }

  const short* bp = biasT + (size_t)(w * HEADS + h) * (NTOK * NTOK);  // [key][query]
  const short* mp = maskT + (size_t)bw * (NTOK * NTOK);               // [key][query]

  for (int rt = wv * 3; rt < wv * 3 + 3; ++rt) {
    const int i0 = rt * 16;
    bf16x8 aq = *(const bf16x8*)(qb + (size_t)(i0 + m) * HD + g * 8);
    f32x4 s[9];
#pragma unroll
    for (int jt = 0; jt < 9; ++jt) {
      bf16x8 bk = *(const bf16x8*)(kb + (size_t)(jt * 16 + m) * HD + g * 8);
      s[jt] = __builtin_amdgcn_mfma_f32_16x16x32_bf16(aq, bk, (f32x4){0.f, 0.f, 0.f, 0.f}, 0, 0, 0);
    }
    // bias + mask (short4: 4 consecutive query rows at fixed key) + row max
    float mx[4] = {-3e38f, -3e38f, -3e38f, -3e38f};
#pragma unroll
    for (int jt = 0; jt < 9; ++jt) {
      int key = jt * 16 + m;
      short4v bb = *(const short4v*)(bp + key * NTOK + i0 + g * 4);
      short4v mm = *(const short4v*)(mp + key * NTOK + i0 + g * 4);
#pragma unroll
      for (int r = 0; r < 4; ++r) {
        float val = s[jt][r] + bf2f(bb[r]) + bf2f(mm[r]);
        s[jt][r] = val;
        mx[r] = fmaxf(mx[r], val);
      }
    }
#pragma unroll
    for (int r = 0; r < 4; ++r) {
      mx[r] = fmaxf(mx[r], __shfl_xor(mx[r], 1, 64));
      mx[r] = fmaxf(mx[r], __shfl_xor(mx[r], 2, 64));
      mx[r] = fmaxf(mx[r], __shfl_xor(mx[r], 4, 64));
      mx[r] = fmaxf(mx[r], __shfl_xor(mx[r], 8, 64));
    }
    float sum[4] = {0.f, 0.f, 0.f, 0.f};
#pragma unroll
    for (int jt = 0; jt < 9; ++jt) {
#pragma unroll
      for (int r = 0; r < 4; ++r) {
        float e = __expf(s[jt][r] - mx[r]);
        s[jt][r] = e;
        sum[r] += e;
      }
    }
#pragma unroll
    for (int r = 0; r < 4; ++r) {
      sum[r] += __shfl_xor(sum[r], 1, 64);
      sum[r] += __shfl_xor(sum[r], 2, 64);
      sum[r] += __shfl_xor(sum[r], 4, 64);
      sum[r] += __shfl_xor(sum[r], 8, 64);
    }
    float rs[4];
#pragma unroll
    for (int r = 0; r < 4; ++r) rs[r] = 1.0f / sum[r];
    // normalized P -> LDS bf16
#pragma unroll
    for (int jt = 0; jt < 9; ++jt)
#pragma unroll
      for (int r = 0; r < 4; ++r)
        myp[(g * 4 + r) * PPITCH + jt * 16 + m] = f2bf(s[jt][r] * rs[r]);

    // O^T = V^T @ P^T (operand-swapped): D rows = d-channels, cols = queries.
    f32x4 o0 = (f32x4){0.f, 0.f, 0.f, 0.f};
    f32x4 o1 = (f32x4){0.f, 0.f, 0.f, 0.f};
#pragma unroll
    for (int kt = 0; kt < 5; ++kt) {
      bf16x8 ap = *(const bf16x8*)(myp + m * PPITCH + kt * 32 + g * 8);
      bf16x8 b0 = *(const bf16x8*)(vt + m * PPITCH + kt * 32 + g * 8);
      bf16x8 b1 = *(const bf16x8*)(vt + (16 + m) * PPITCH + kt * 32 + g * 8);
      o0 = __builtin_amdgcn_mfma_f32_16x16x32_bf16(b0, ap, o0, 0, 0, 0);
      o1 = __builtin_amdgcn_mfma_f32_16x16x32_bf16(b1, ap, o1, 0, 0, 0);
    }
    // lane: token = i0+m, d = g*4+r (o0) / 16+g*4+r (o1) -> two short4 stores
    size_t ob = ((size_t)(bw * NTOK + i0 + m)) * DIM + h * HD + g * 4;
    short4v s0, s1;
#pragma unroll
    for (int r = 0; r < 4; ++r) { s0[r] = f2bf(o0[r]); s1[r] = f2bf(o1[r]); }
    *(short4v*)(aout + ob) = s0;
    *(short4v*)(aout + ob + 16) = s1;
  }
}

// ---------------------------------------------------------------------------
// Proj GEMM, operand-swapped: block = 32 tokens x 192 channels, ain tile in
// LDS; wave = 48 ch x 32 tok (3x2 frags, 24 AGPR). Lane stores float4 (16 B,
// 4 consecutive channels x 1 token) — 6 stores vs 48 scalar dwords.
// ---------------------------------------------------------------------------
__global__ __launch_bounds__(256, 2) void proj_gemm(
    const short* __restrict__ ain, const short* __restrict__ pw,
    const float* __restrict__ pb, float* __restrict__ out)
{
  __shared__ __align__(16) short as_[32 * XPITCH];
  const int t0 = blockIdx.x * 32;

  { // stage ain tile (bf16 copy)
    const int row = threadIdx.x >> 3;
    const int cg  = threadIdx.x & 7;
    const short* sp = ain + (size_t)(t0 + row) * DIM + cg * 24;
    short* dstp = as_ + row * XPITCH + cg * 24;
#pragma unroll
    for (int i = 0; i < 3; ++i)
      *(bf16x8*)(dstp + i * 8) = *(const bf16x8*)(sp + i * 8);
  }
  __syncthreads();

  const int wave = threadIdx.x >> 6, lane = threadIdx.x & 63;
  const int m = lane & 15, g = lane >> 4;
  const int c0w = wave * 48;

  f32x4 acc[3][2];
#pragma unroll
  for (int ct = 0; ct < 3; ++ct)
#pragma unroll
    for (int rt = 0; rt < 2; ++rt) acc[ct][rt] = (f32x4){0.f, 0.f, 0.f, 0.f};

  for (int ks = 0; ks < 6; ++ks) {
    const int kk = ks * 32 + g * 8;
    bf16x8 b0 = *(const bf16x8*)(as_ + m * XPITCH + kk);
    bf16x8 b1 = *(const bf16x8*)(as_ + (16 + m) * XPITCH + kk);
#pragma unroll
    for (int ct = 0; ct < 3; ++ct) {
      bf16x8 a = *(const bf16x8*)(pw + (size_t)(c0w + ct * 16 + m) * DIM + kk);
      acc[ct][0] = __builtin_amdgcn_mfma_f32_16x16x32_bf16(a, b0, acc[ct][0], 0, 0, 0);
      acc[ct][1] = __builtin_amdgcn_mfma_f32_16x16x32_bf16(a, b1, acc[ct][1], 0, 0, 0);
    }
  }

#pragma unroll
  for (int ct = 0; ct < 3; ++ct) {
    int co0 = c0w + ct * 16 + g * 4;
    float4 b4 = *(const float4*)(pb + co0);
#pragma unroll
    for (int rt = 0; rt < 2; ++rt) {
      int tok = t0 + rt * 16 + m;
      float4 o;
      o.x = acc[ct][rt][0] + b4.x;
      o.y = acc[ct][rt][1] + b4.y;
      o.z = acc[ct][rt][2] + b4.z;
      o.w = acc[ct][rt][3] + b4.w;
      *(float4*)(out + (size_t)tok * DIM + co0) = o;
    }
  }
}

// ---------------------------------------------------------------------------
extern "C" void kernel_launch(void* const* d_in, const int* in_sizes, int n_in,
                              void* d_out, int out_size, void* d_ws, size_t ws_size,
                              hipStream_t stream) {
  const float* x          = (const float*)d_in[0];
  const float* mask       = (const float*)d_in[1];
  const float* qkv_w      = (const float*)d_in[2];
  const float* qkv_b      = (const float*)d_in[3];
  const float* proj_w     = (const float*)d_in[4];
  const float* proj_b     = (const float*)d_in[5];
  const float* bias_table = (const float*)d_in[6];
  const int*   pos_index  = (const int*)d_in[7];
  float* out = (float*)d_out;

  // workspace carve (16B-aligned)
  const size_t NELEM = (size_t)TOKENS * DIM;   // 26,542,080
  short* qv    = (short*)d_ws;
  short* kv    = qv + NELEM;
  short* vv    = kv + NELEM;
  short* aout  = vv + NELEM;
  short* wqb   = aout + NELEM;
  short* wpb   = wqb + NWQ;
  short* biasT = wpb + NWP;
  short* maskT = biasT + NBIAS;
  // total = 4*NELEM + NWQ + NWP + NBIAS + NMASK shorts ≈ 260.4 MB

  prep_kernel<<<(NB8 + NM8 + NWQ8 + NWP8 + 255) / 256, 256, 0, stream>>>(
      qkv_w, proj_w, bias_table, pos_index, mask, wqb, wpb, biasT, maskT);
  qkv_gemm<<<TOKENS / 32, 256, 0, stream>>>(x, wqb, qkv_b, qv, kv, vv);
  attn_kernel<<<NBWH, 192, 0, stream>>>(qv, kv, vv, biasT, maskT, aout);
  proj_gemm<<<TOKENS / 32, 256, 0, stream>>>(aout, wpb, proj_b, out);
}